// Round 8
// baseline (3469.269 us; speedup 1.0000x reference)
//
#include <hip/hip_runtime.h>
#include <stdint.h>

// ---------------------------------------------------------------------------
// GRU encoder (B=128,T=512,D=512,H=512,L=256), MI355X gfx950.
//
// R8: h exchange through the XCD-local L2.
//  - group = blockIdx & 7: under round-robin workgroup->XCD dispatch, the 8
//    blocks of a group share one XCD's L2 (coherent within XCD, ~200cy RT).
//  - dual-path tagged exchange (h dword = bf16<<16 | tag):
//      producer: 4 plain stores -> fastbuf (local L2) AND 4 sc0 sc1 stores
//                -> slowbuf (authoritative at MALL). fire-and-forget.
//      consumer: coop sc0 loads of fastbuf (L1 bypass, L2 served); tag
//                mismatch -> retry; attempts 3,5,7.. use slowbuf via sc1.
//    Correct regardless of XCD placement (tags reject stale; slow path
//    guarantees progress); fast iff placement cooperates.
//  - LDS staging with 16B-chunk XOR swizzle (c ^= row&7, rows 1024B) on both
//    write and read: kills R7's 8-way superbank conflicts (2.1e7 -> ~0).
//  - IG[t+1] prefetch issued AFTER the vote loop so its HBM latency is not
//    inside the fast path's vmcnt(0).
//  - no atomics / sleeps / memsets. Vote __syncthreads_or doubles as the
//    LDS WAR barrier. Poison 0xAAAA != any tag 1..511; t=0 skips h.
// ---------------------------------------------------------------------------

typedef short short8 __attribute__((ext_vector_type(8)));
typedef float f32x4 __attribute__((ext_vector_type(4)));
typedef int int4v __attribute__((ext_vector_type(4)));
typedef unsigned int uint;

#define NB 128
#define NT 512
#define ND 512
#define NH 512
#define NG 1536  // 3H

__device__ __forceinline__ unsigned short f2bf(float f) {
  union { float f; unsigned u; } v; v.f = f;
  unsigned r = v.u + 0x7fffu + ((v.u >> 16) & 1u);  // RNE
  return (unsigned short)(r >> 16);
}
__device__ __forceinline__ float bf2f(unsigned short u) {
  union { unsigned u; float f; } v; v.u = ((unsigned)u) << 16; return v.f;
}
__device__ __forceinline__ float sigmoid_f(float x) {
  float e = __builtin_amdgcn_exp2f(-1.4426950408889634f * x);
  return __builtin_amdgcn_rcpf(1.0f + e);
}
__device__ __forceinline__ float tanh_f(float x) {
  float e = __builtin_amdgcn_exp2f(2.8853900817779268f * x);
  return 1.0f - 2.0f * __builtin_amdgcn_rcpf(1.0f + e);
}
__device__ __forceinline__ short8 pack8(float4 a, float4 b) {
  short8 s;
  s[0] = (short)f2bf(a.x); s[1] = (short)f2bf(a.y);
  s[2] = (short)f2bf(a.z); s[3] = (short)f2bf(a.w);
  s[4] = (short)f2bf(b.x); s[5] = (short)f2bf(b.y);
  s[6] = (short)f2bf(b.z); s[7] = (short)f2bf(b.w);
  return s;
}

// 8 dwordx4 coop loads (this thread's 32 tagged dwords) + drain.
// FAST: sc0 only -> bypass L1, served by the XCD-local L2.
__device__ __forceinline__ void coop8_fast(const uint* p, int4v a[8]) {
  asm volatile(
      "global_load_dwordx4 %0, %8, off sc0\n\t"
      "global_load_dwordx4 %1, %8, off offset:16 sc0\n\t"
      "global_load_dwordx4 %2, %8, off offset:32 sc0\n\t"
      "global_load_dwordx4 %3, %8, off offset:48 sc0\n\t"
      "global_load_dwordx4 %4, %8, off offset:64 sc0\n\t"
      "global_load_dwordx4 %5, %8, off offset:80 sc0\n\t"
      "global_load_dwordx4 %6, %8, off offset:96 sc0\n\t"
      "global_load_dwordx4 %7, %8, off offset:112 sc0\n\t"
      "s_waitcnt vmcnt(0)"
      : "=&v"(a[0]), "=&v"(a[1]), "=&v"(a[2]), "=&v"(a[3]),
        "=&v"(a[4]), "=&v"(a[5]), "=&v"(a[6]), "=&v"(a[7])
      : "v"(p)
      : "memory");
}
// SLOW: sc0 sc1 -> coherence point (proven R3-R7).
__device__ __forceinline__ void coop8_slow(const uint* p, int4v a[8]) {
  asm volatile(
      "global_load_dwordx4 %0, %8, off sc0 sc1\n\t"
      "global_load_dwordx4 %1, %8, off offset:16 sc0 sc1\n\t"
      "global_load_dwordx4 %2, %8, off offset:32 sc0 sc1\n\t"
      "global_load_dwordx4 %3, %8, off offset:48 sc0 sc1\n\t"
      "global_load_dwordx4 %4, %8, off offset:64 sc0 sc1\n\t"
      "global_load_dwordx4 %5, %8, off offset:80 sc0 sc1\n\t"
      "global_load_dwordx4 %6, %8, off offset:96 sc0 sc1\n\t"
      "global_load_dwordx4 %7, %8, off offset:112 sc0 sc1\n\t"
      "s_waitcnt vmcnt(0)"
      : "=&v"(a[0]), "=&v"(a[1]), "=&v"(a[2]), "=&v"(a[3]),
        "=&v"(a[4]), "=&v"(a[5]), "=&v"(a[6]), "=&v"(a[7])
      : "v"(p)
      : "memory");
}

// ---------------------------------------------------------------------------
// IG = x @ Wih^T + bias, bf16, wave-tile layout (verified R5-R7):
// IG[(((g*NT+t)*32+cc)*3+gt)*256 + (q*16+l15)*4 + i]
// ---------------------------------------------------------------------------
__global__ __launch_bounds__(256) void ig_gemm(
    const float* __restrict__ x, const float* __restrict__ Wih,
    const float* __restrict__ bias, unsigned short* __restrict__ IG) {
  __shared__ unsigned short As[128 * 40];
  __shared__ unsigned short Bs[128 * 40];
  const int tid = threadIdx.x;
  const int bm = blockIdx.x, bn = blockIdx.y;
  const int lane = tid & 63, w = tid >> 6;
  const int wm = w >> 1, wn = w & 1;
  const int l15 = lane & 15, q = lane >> 4;

  f32x4 acc[4][4] = {};

  for (int kt = 0; kt < 16; ++kt) {
    __syncthreads();
#pragma unroll
    for (int j = 0; j < 4; ++j) {
      int fi = tid + 256 * j;
      int row = fi >> 3, kq = fi & 7;
      float4 v = *(const float4*)(x + (size_t)(bm * 128 + row) * ND + kt * 32 + kq * 4);
      ushort4 s = {f2bf(v.x), f2bf(v.y), f2bf(v.z), f2bf(v.w)};
      *(ushort4*)&As[row * 40 + kq * 4] = s;
    }
#pragma unroll
    for (int j = 0; j < 4; ++j) {
      int fi = tid + 256 * j;
      int row = fi >> 3, kq = fi & 7;
      float4 v = *(const float4*)(Wih + (size_t)(bn * 128 + row) * ND + kt * 32 + kq * 4);
      ushort4 s = {f2bf(v.x), f2bf(v.y), f2bf(v.z), f2bf(v.w)};
      *(ushort4*)&Bs[row * 40 + kq * 4] = s;
    }
    __syncthreads();

    short8 af[4], bf[4];
#pragma unroll
    for (int tm = 0; tm < 4; ++tm)
      af[tm] = *(const short8*)&As[(wm * 64 + tm * 16 + l15) * 40 + q * 8];
#pragma unroll
    for (int tn = 0; tn < 4; ++tn)
      bf[tn] = *(const short8*)&Bs[(wn * 64 + tn * 16 + l15) * 40 + q * 8];
#pragma unroll
    for (int tm = 0; tm < 4; ++tm)
#pragma unroll
      for (int tn = 0; tn < 4; ++tn)
        acc[tm][tn] = __builtin_amdgcn_mfma_f32_16x16x32_bf16(af[tm], bf[tn], acc[tm][tn], 0, 0, 0);
  }

  const int b = bm >> 2;
  const int bt_ = b >> 4, qc = (b >> 2) & 3, ic = b & 3;
  const int tb = (bm & 3) * 128 + wm * 64;
#pragma unroll
  for (int tm = 0; tm < 4; ++tm) {
#pragma unroll
    for (int tn = 0; tn < 4; ++tn) {
      int C = bn * 128 + wn * 64 + tn * 16 + l15;
      int gt_ = C >> 9, hcol = C & 511, cc_ = hcol >> 4;
      float bb = bias[C];
#pragma unroll
      for (int i = 0; i < 4; ++i) {
        int t = tb + tm * 16 + q * 4 + i;
        size_t idx = ((((size_t)bt_ * NT + t) * 32 + cc_) * 3 + gt_) * 256
                     + (size_t)(qc * 16 + l15) * 4 + ic;
        IG[idx] = f2bf(acc[tm][tn][i] + bb);
      }
    }
  }
}

// ---------------------------------------------------------------------------
// Persistent GRU recurrence. 64 blocks x 256 threads.
// group g = blockIdx & 7  (XCD-aligned under round-robin dispatch)
// col-chunk cb = blockIdx >> 3 (64 cols); wave w owns 16 cols.
// ---------------------------------------------------------------------------
template <bool USE_IG>
__global__ __launch_bounds__(256, 1) void gru_rec(
    const float* __restrict__ x, const float* __restrict__ Wih,
    const float* __restrict__ Whh, const float* __restrict__ bias,
    const float* __restrict__ bn, const unsigned short* __restrict__ IG,
    uint* __restrict__ fastb, uint* __restrict__ slowb,
    float* __restrict__ hfin) {
  const int tid = threadIdx.x;
  const int lane = tid & 63;
  const int w = tid >> 6;          // wave 0..3
  const int l15 = lane & 15, q = lane >> 4;
  const int g = blockIdx.x & 7;    // batch group (rows g*16..+16) = XCD id
  const int cb = blockIdx.x >> 3;  // col-chunk of 64
  const int col = cb * 64 + w * 16 + l15;  // this lane's h column
  const int cc = cb * 4 + w;               // col-16-chunk id (IG layout)
  const int mrow = g * 16 + l15;           // A-fragment batch row
  const int erow = g * 16 + q * 4;         // C-layout batch row base
  const int lrow = tid & 15;               // coop loader: local row
  const int lseg = tid >> 4;               // coop loader: 32-dword segment

  __shared__ unsigned short hA[16 * 512];  // 16 KB, XOR-swizzled chunks

  // Whh B-fragments -> registers: 3 gates x 16 k-chunks (192 VGPRs)
  short8 bfr[3][16];
#pragma unroll
  for (int gt = 0; gt < 3; ++gt) {
    const float* src = Whh + (size_t)(gt * NH + col) * NH + q * 8;
#pragma unroll
    for (int kk = 0; kk < 16; ++kk) {
      float4 v0 = *(const float4*)(src + kk * 32);
      float4 v1 = *(const float4*)(src + kk * 32 + 4);
      bfr[gt][kk] = pack8(v0, v1);
    }
  }

  float bi_r = 0.f, bi_z = 0.f, bi_n = 0.f;
  if (!USE_IG) {
    bi_r = bias[col];
    bi_z = bias[NH + col];
    bi_n = bias[2 * NH + col];
  }
  const float bnv = bn[col];

  float hreg[4] = {0.f, 0.f, 0.f, 0.f};

  // preload IG[0]
  uint2 cr = {}, cz = {}, cn = {};
  if (USE_IG) {
    const unsigned short* p0 =
        IG + (((size_t)g * NT + 0) * 32 + cc) * 768 + (size_t)(q * 16 + l15) * 4;
    cr = *(const uint2*)p0;
    cz = *(const uint2*)(p0 + 256);
    cn = *(const uint2*)(p0 + 512);
  }

  for (int t = 0; t < NT; ++t) {
    // h @ Whh^T via dual-path coop load + block vote + swizzled LDS
    f32x4 ar = {0.f, 0.f, 0.f, 0.f};
    f32x4 az = {0.f, 0.f, 0.f, 0.f};
    f32x4 an = {0.f, 0.f, 0.f, 0.f};
    if (t > 0) {
      const size_t off = (size_t)((t & 1) ? NB * NH : 0) +
                         (size_t)(g * 16 + lrow) * NH + lseg * 32;
      const uint* fp = fastb + off;
      const uint* sp = slowb + off;
      const uint tt = (uint)t;
      int4v raw[8];
      int attempt = 0;
      uint acc_;
      do {
        if (attempt >= 3 && (attempt & 1)) coop8_slow(sp, raw);
        else coop8_fast(fp, raw);
        ++attempt;
        acc_ = 0;
#pragma unroll
        for (int j = 0; j < 8; ++j) {
          acc_ |= ((uint)raw[j][0] ^ tt); acc_ |= ((uint)raw[j][1] ^ tt);
          acc_ |= ((uint)raw[j][2] ^ tt); acc_ |= ((uint)raw[j][3] ^ tt);
        }
      } while (__syncthreads_or((int)(acc_ & 0xffffu)));
      // vote barrier passed: also the WAR barrier for hA reuse.

      // strip tags -> LDS, XOR-swizzled 16B chunks: chunk c' = c ^ (row&7)
      unsigned short* base = &hA[lrow * 512];
#pragma unroll
      for (int j = 0; j < 4; ++j) {
        int4v s;
        s[0] = (int)__builtin_amdgcn_perm((uint)raw[2 * j][1], (uint)raw[2 * j][0], 0x07060302u);
        s[1] = (int)__builtin_amdgcn_perm((uint)raw[2 * j][3], (uint)raw[2 * j][2], 0x07060302u);
        s[2] = (int)__builtin_amdgcn_perm((uint)raw[2 * j + 1][1], (uint)raw[2 * j + 1][0], 0x07060302u);
        s[3] = (int)__builtin_amdgcn_perm((uint)raw[2 * j + 1][3], (uint)raw[2 * j + 1][2], 0x07060302u);
        int cx = (lseg * 4 + j) ^ (lrow & 7);
        *(int4v*)(base + cx * 8) = s;
      }
      __syncthreads();
#pragma unroll
      for (int kk = 0; kk < 16; ++kk) {
        int cx = (kk * 4 + q) ^ (l15 & 7);
        short8 afk = *(const short8*)&hA[l15 * 512 + cx * 8];
        ar = __builtin_amdgcn_mfma_f32_16x16x32_bf16(afk, bfr[0][kk], ar, 0, 0, 0);
        az = __builtin_amdgcn_mfma_f32_16x16x32_bf16(afk, bfr[1][kk], az, 0, 0, 0);
        an = __builtin_amdgcn_mfma_f32_16x16x32_bf16(afk, bfr[2][kk], an, 0, 0, 0);
      }
    }

    // prefetch IG[t+1] AFTER the exchange so its HBM latency is off the
    // fast path's vmcnt(0); consumed at next step's gates (~1 step slack).
    uint2 nr = {}, nz = {}, nn = {};
    if (USE_IG) {
      int tn_ = (t + 1 < NT) ? t + 1 : t;
      const unsigned short* pn =
          IG + (((size_t)g * NT + tn_) * 32 + cc) * 768 + (size_t)(q * 16 + l15) * 4;
      nr = *(const uint2*)pn;
      nz = *(const uint2*)(pn + 256);
      nn = *(const uint2*)(pn + 512);
    }

    // fallback: x@Wih^T (independent of h)
    f32x4 axr = {0.f, 0.f, 0.f, 0.f};
    f32x4 axz = {0.f, 0.f, 0.f, 0.f};
    f32x4 axn = {0.f, 0.f, 0.f, 0.f};
    if (!USE_IG) {
#pragma unroll
      for (int kk = 0; kk < 16; ++kk) {
        const float* xp = x + ((size_t)mrow * NT + t) * ND + kk * 32 + q * 8;
        short8 xa = pack8(*(const float4*)xp, *(const float4*)(xp + 4));
#pragma unroll
        for (int gt = 0; gt < 3; ++gt) {
          const float* wp = Wih + (size_t)(gt * NH + col) * ND + kk * 32 + q * 8;
          short8 wf = pack8(*(const float4*)wp, *(const float4*)(wp + 4));
          if (gt == 0) axr = __builtin_amdgcn_mfma_f32_16x16x32_bf16(xa, wf, axr, 0, 0, 0);
          if (gt == 1) axz = __builtin_amdgcn_mfma_f32_16x16x32_bf16(xa, wf, axz, 0, 0, 0);
          if (gt == 2) axn = __builtin_amdgcn_mfma_f32_16x16x32_bf16(xa, wf, axn, 0, 0, 0);
        }
      }
    }

    // gates + h update
    float igr[4], igz[4], ign[4];
    if (USE_IG) {
      igr[0] = bf2f((unsigned short)(cr.x & 0xffff));
      igr[1] = bf2f((unsigned short)(cr.x >> 16));
      igr[2] = bf2f((unsigned short)(cr.y & 0xffff));
      igr[3] = bf2f((unsigned short)(cr.y >> 16));
      igz[0] = bf2f((unsigned short)(cz.x & 0xffff));
      igz[1] = bf2f((unsigned short)(cz.x >> 16));
      igz[2] = bf2f((unsigned short)(cz.y & 0xffff));
      igz[3] = bf2f((unsigned short)(cz.y >> 16));
      ign[0] = bf2f((unsigned short)(cn.x & 0xffff));
      ign[1] = bf2f((unsigned short)(cn.x >> 16));
      ign[2] = bf2f((unsigned short)(cn.y & 0xffff));
      ign[3] = bf2f((unsigned short)(cn.y >> 16));
    }
    uint sv[4];
#pragma unroll
    for (int i = 0; i < 4; ++i) {
      float xr = ar[i] + (USE_IG ? igr[i] : (axr[i] + bi_r));
      float xz = az[i] + (USE_IG ? igz[i] : (axz[i] + bi_z));
      float xin = USE_IG ? ign[i] : (axn[i] + bi_n);
      float r = sigmoid_f(xr);
      float z = sigmoid_f(xz);
      float n = tanh_f(xin + r * (an[i] + bnv));
      float h2 = (1.f - z) * n + z * hreg[i];
      hreg[i] = h2;
      sv[i] = ((uint)f2bf(h2) << 16) | (uint)(t + 1);
      if (t == NT - 1) hfin[(size_t)(erow + i) * NH + col] = h2;
    }
    if (t != NT - 1) {
      const size_t soff = (size_t)((t & 1) ? 0 : NB * NH) + (size_t)erow * NH + col;
      uint* f0 = fastb + soff;
      uint* f1 = f0 + 2 * NH;
      uint* s0 = slowb + soff;
      uint* s1 = s0 + 2 * NH;
      asm volatile(
          "global_store_dword %0, %4, off\n\t"            // fast: local L2
          "global_store_dword %0, %5, off offset:2048\n\t"
          "global_store_dword %1, %6, off\n\t"
          "global_store_dword %1, %7, off offset:2048\n\t"
          "global_store_dword %2, %4, off sc0 sc1\n\t"    // slow: MALL
          "global_store_dword %2, %5, off offset:2048 sc0 sc1\n\t"
          "global_store_dword %3, %6, off sc0 sc1\n\t"
          "global_store_dword %3, %7, off offset:2048 sc0 sc1"
          :
          : "v"(f0), "v"(f1), "v"(s0), "v"(s1),
            "v"(sv[0]), "v"(sv[1]), "v"(sv[2]), "v"(sv[3])
          : "memory");
    }
    cr = nr; cz = nz; cn = nn;
  }
}

// ---------------------------------------------------------------------------
// out = h_T @ Wlin^T + blin; mu = cols [0,256), logvar = cols [256,512).
// ---------------------------------------------------------------------------
__global__ __launch_bounds__(256) void final_linear(
    const float* __restrict__ hfin, const float* __restrict__ Wlin,
    const float* __restrict__ blin, float* __restrict__ out) {
  __shared__ float sh[16 * 516];
  const int tid = threadIdx.x;
  const int b0 = blockIdx.y * 16, o0 = blockIdx.x * 16;

  for (int j = tid; j < 16 * 128; j += 256) {
    int row = j >> 7, kq = j & 127;
    *(float4*)&sh[row * 516 + kq * 4] =
        *(const float4*)(hfin + (size_t)(b0 + row) * NH + kq * 4);
  }
  __syncthreads();

  const int bi = tid & 15, oi = tid >> 4;
  const int o = o0 + oi;
  const float4* wp = (const float4*)(Wlin + (size_t)o * NH);
  float4 a4 = {0.f, 0.f, 0.f, 0.f};
  for (int k4 = 0; k4 < 128; ++k4) {
    float4 wv = wp[k4];
    float4 hv = *(const float4*)&sh[bi * 516 + k4 * 4];
    a4.x += wv.x * hv.x; a4.y += wv.y * hv.y;
    a4.z += wv.z * hv.z; a4.w += wv.w * hv.w;
  }
  float v = a4.x + a4.y + a4.z + a4.w + blin[o];
  int b = b0 + bi;
  if (o < 256) out[b * 256 + o] = v;
  else out[32768 + b * 256 + (o - 256)] = v;
}

// ---------------------------------------------------------------------------
extern "C" void kernel_launch(void* const* d_in, const int* in_sizes, int n_in,
                              void* d_out, int out_size, void* d_ws, size_t ws_size,
                              hipStream_t stream) {
  const float* x    = (const float*)d_in[0];
  const float* Wih  = (const float*)d_in[1];
  const float* Whh  = (const float*)d_in[2];
  const float* bias = (const float*)d_in[3];
  const float* bn   = (const float*)d_in[4];
  const float* Wlin = (const float*)d_in[5];
  const float* blin = (const float*)d_in[6];
  float* out = (float*)d_out;

  char* ws = (char*)d_ws;
  // layout: [fastbuf 524288][slowbuf 524288][hfin 262144][IG 201326592]
  uint* fastb         = (uint*)ws;
  uint* slowb         = (uint*)(ws + 524288);
  float* hfin         = (float*)(ws + 1048576);
  unsigned short* IG  = (unsigned short*)(ws + 1310720);
  const size_t need_min = 1310720;
  const size_t need_ig  = 1310720 + (size_t)NB * NT * NG * 2;  // ~203 MB
  if (ws_size < need_min) return;
  // no memsets: t=0 skips h reads; tags reject 0xAAAA poison.

  const bool useIG = (ws_size >= need_ig);
  if (useIG) {
    ig_gemm<<<dim3(512, 12), 256, 0, stream>>>(x, Wih, bias, IG);
    gru_rec<true><<<64, 256, 0, stream>>>(x, Wih, Whh, bias, bn, IG, fastb, slowb, hfin);
  } else {
    gru_rec<false><<<64, 256, 0, stream>>>(x, Wih, Whh, bias, bn, nullptr, fastb, slowb, hfin);
  }
  final_linear<<<dim3(32, 8), 256, 0, stream>>>(hfin, Wlin, blin, out);
}